// Round 12
// baseline (303.067 us; speedup 1.0000x reference)
//
#include <hip/hip_runtime.h>
#include <math.h>

// QMIX mixing network, B=65536, A=8, S=256, E=32. All tensors fp32.
// Transposed MFMA: A-operand = bf16(Wcat^T) fragments (m = out col),
// B-operand = bf16(states) (n = batch row), mfma_f32_16x16x32_bf16.
// PERSISTENT-WEIGHTS design: grid 256 x 256 threads (4 waves, 1 block/CU).
// 19 of 22 weight tiles (152 KB) staged ONCE per block into LDS via
// global_load_lds (single barrier); 3 tiles/chunk streamed from L2 with
// depth-1 register prefetch. Block then loops 4 x 64-row tiles, single-B
// (16 rows/wave, acc = 88 AGPR) with the R6-proven states pipeline.
// Register lesson (R8/R9/R11 spills): dual-B acc=176 AGPR + prefetch state
// always spills or caps at 1 wave/SIMD; single-B (~220 unified) gives
// 2 waves/SIMD AND the persistent LDS image kills the weight re-staging
// that made single-B lose in R10.
// Wcat columns: [0,256)=w1_W, [256,288)=wf_W, [288,320)=b1_W, [320,352)=v1_W.

#define NTILES 22      // 352/16
#define KCHUNKS 8      // 256/32
#define LDS_TILES 19   // tiles resident in LDS
#define LDS_SLOTS (LDS_TILES * KCHUNKS)   // 152 slots x 1 KB = 155648 B
#define ROWTILES 4     // 64-row tiles per block

typedef __attribute__((ext_vector_type(8))) short short8;
typedef __attribute__((ext_vector_type(4))) float float4v;

__device__ __forceinline__ unsigned short f2b(float f) {
    unsigned int u = __float_as_uint(f);
    u = u + 0x7fffu + ((u >> 16) & 1u);   // RNE
    return (unsigned short)(u >> 16);
}

// Direct global->LDS DMA, 16 B/lane. LDS dest = wave-uniform base + lane*16.
__device__ __forceinline__ void gl2lds16(const unsigned short* g, unsigned short* l) {
    __builtin_amdgcn_global_load_lds(
        (const __attribute__((address_space(1))) unsigned int*)g,
        (__attribute__((address_space(3))) unsigned int*)l,
        16, 0, 0);
}

// Repack fp32 Wcat into bf16 A-fragment slots of 64 lanes x 16 B:
//   t < 19:  slot = t*8 + kc      (contiguous 152 KB LDS image)
//   t >= 19: slot = 152 + kc*3 + (t-19)   (per-chunk stream, 3 KB contiguous)
// brep[(slot*64 + lane)*8 + j] = bf16(Wcat[k = kc*32+(lane>>4)*8+j][t*16+(lane&15)])
__global__ void repack_b(const float* __restrict__ w1_W,
                         const float* __restrict__ wf_W,
                         const float* __restrict__ b1_W,
                         const float* __restrict__ v1_W,
                         unsigned short* __restrict__ brep) {
    int idx = blockIdx.x * 256 + threadIdx.x;   // 0..11263
    int lane = idx & 63;
    int slot = idx >> 6;          // 0..175
    int t, kc;
    if (slot < LDS_SLOTS) { t = slot >> 3; kc = slot & 7; }
    else { int r = slot - LDS_SLOTS; kc = r / 3; t = LDS_TILES + r % 3; }
    int kbase = kc * 32 + (lane >> 4) * 8;
    int n = t * 16 + (lane & 15);
    short8 frag;
#pragma unroll
    for (int j = 0; j < 8; ++j) {
        int k = kbase + j;
        float val;
        if (n < 256)      val = w1_W[k * 256 + n];
        else if (n < 288) val = wf_W[k * 32 + (n - 256)];
        else if (n < 320) val = b1_W[k * 32 + (n - 288)];
        else              val = v1_W[k * 32 + (n - 320)];
        frag[j] = (short)f2b(val);
    }
    *(short8*)(&brep[idx * 8]) = frag;
}

__global__ void __launch_bounds__(256, 2)
qmix_main(const float* __restrict__ agent_qs,
          const float* __restrict__ states,
          const unsigned short* __restrict__ brep,
          const float* __restrict__ w1_b,
          const float* __restrict__ wf_b,
          const float* __restrict__ b1_b,
          const float* __restrict__ v1_b,
          const float* __restrict__ v2_W,
          const float* __restrict__ v2_b,
          float* __restrict__ out) {
    __shared__ __align__(16) unsigned short wlds[LDS_SLOTS * 512];   // 155648 B

    const int tid  = threadIdx.x;
    const int wave = tid >> 6, lane = tid & 63;
    const int quad = lane >> 4, l16 = lane & 15;

    // ---- Stage 19 tiles (152 KB) into LDS once: 38 DMAs per wave ----
    for (int s = wave; s < LDS_SLOTS; s += 4)
        gl2lds16(brep + (size_t)(s * 64 + lane) * 8, wlds + s * 512);
    __syncthreads();   // the ONLY barrier; wlds read-only below

    const short8* wl = (const short8*)wlds + lane;                    // + (t*8+kc)*64
    const short8* ws = (const short8*)brep + LDS_SLOTS * 64 + lane;   // + (kc*3+u)*64

    for (int tt = 0; tt < ROWTILES; ++tt) {
        const int row = blockIdx.x * (ROWTILES * 64) + tt * 64 + wave * 16 + l16;
        const float* srow = states + (size_t)row * 256;

        // States pipeline depth 1 (R6-proven shape)
        float4v s0a = *(const float4v*)(srow + quad * 8);
        float4v s0b = *(const float4v*)(srow + quad * 8 + 4);
        // Streamed-tile prefetch depth 1
        short8 sf[2][3];
#pragma unroll
        for (int u = 0; u < 3; ++u) sf[0][u] = ws[u * 64];

        float4v acc[NTILES];
#pragma unroll
        for (int t = 0; t < NTILES; ++t)
#pragma unroll
            for (int q = 0; q < 4; ++q) acc[t][q] = 0.f;

#pragma unroll
        for (int kc = 0; kc < KCHUNKS; ++kc) {
            // Prefetch next streamed frags (1 ahead)
            if (kc + 1 < KCHUNKS) {
#pragma unroll
                for (int u = 0; u < 3; ++u)
                    sf[(kc + 1) & 1][u] = ws[((kc + 1) * 3 + u) * 64];
            }
            // Convert current states frag to bf16
            short8 b0;
#pragma unroll
            for (int j = 0; j < 4; ++j) {
                b0[j] = (short)f2b(s0a[j]); b0[4 + j] = (short)f2b(s0b[j]);
            }
            // Prefetch next states frag
            if (kc + 1 < KCHUNKS) {
                const float* p0 = srow + (kc + 1) * 32 + quad * 8;
                s0a = *(const float4v*)(p0);
                s0b = *(const float4v*)(p0 + 4);
            }
            // 19 LDS tiles: ds_read_b128 feeds MFMA
#pragma unroll
            for (int t = 0; t < LDS_TILES; ++t) {
                short8 af = wl[(t * 8 + kc) * 64];
                acc[t] = __builtin_amdgcn_mfma_f32_16x16x32_bf16(af, b0, acc[t], 0, 0, 0);
            }
            // 3 streamed tiles
#pragma unroll
            for (int u = 0; u < 3; ++u)
                acc[LDS_TILES + u] = __builtin_amdgcn_mfma_f32_16x16x32_bf16(
                    sf[kc & 1][u], b0, acc[LDS_TILES + u], 0, 0, 0);
        }

        // ---- Epilogue (all in registers; R4-R11 verified mapping) ----
        float4v q0 = *(const float4v*)(agent_qs + (size_t)row * 8);
        float4v q1 = *(const float4v*)(agent_qs + (size_t)row * 8 + 4);
        float qv[8] = {q0[0], q0[1], q0[2], q0[3], q1[0], q1[1], q1[2], q1[3]};

        float qacc[8], wfv[8], b1v[8], svp = 0.f;
#pragma unroll
        for (int s = 0; s < 8; ++s) qacc[s] = 0.f;

#pragma unroll
        for (int t = 0; t < NTILES; ++t) {
            const float* bptr =
                (t < 16) ? (w1_b + t * 16) :
                (t < 18) ? (wf_b + (t - 16) * 16) :
                (t < 20) ? (b1_b + (t - 18) * 16) : (v1_b + (t - 20) * 16);
            float4v bb = *(const float4v*)(bptr + quad * 4);
            float vb[4];
#pragma unroll
            for (int j = 0; j < 4; ++j) vb[j] = acc[t][j] + bb[j];

            if (t < 16) {              // w1: agent a = t>>1, slot base = (t&1)*4
                float q = qv[t >> 1];
                int base = (t & 1) * 4;
#pragma unroll
                for (int j = 0; j < 4; ++j) qacc[base + j] += q * fabsf(vb[j]);
            } else if (t < 18) {       // w_final
                int base = (t - 16) * 4;
#pragma unroll
                for (int j = 0; j < 4; ++j) wfv[base + j] = fabsf(vb[j]);
            } else if (t < 20) {       // b1
                int base = (t - 18) * 4;
#pragma unroll
                for (int j = 0; j < 4; ++j) b1v[base + j] = vb[j];
            } else {                   // V hidden: relu -> dot v2_W
                int ebase = (t - 20) * 16 + quad * 4;
#pragma unroll
                for (int j = 0; j < 4; ++j)
                    svp += fmaxf(vb[j], 0.f) * v2_W[ebase + j];
            }
        }

        float mix = 0.f;
#pragma unroll
        for (int s = 0; s < 8; ++s) {
            float h = qacc[s] + b1v[s];
            h = h > 0.f ? h : (__expf(h) - 1.f);   // elu, alpha=1
            mix += h * wfv[s];
        }
        float tot = mix + svp;                      // partial over this quad's e-subset
        tot += __shfl_xor(tot, 16);                 // combine 4 quads (same batch row)
        tot += __shfl_xor(tot, 32);
        if (quad == 0) out[row] = tot + v2_b[0];
    }
}

extern "C" void kernel_launch(void* const* d_in, const int* in_sizes, int n_in,
                              void* d_out, int out_size, void* d_ws, size_t ws_size,
                              hipStream_t stream) {
    const float* agent_qs = (const float*)d_in[0];
    const float* states   = (const float*)d_in[1];
    const float* w1_W = (const float*)d_in[2];
    const float* w1_b = (const float*)d_in[3];
    const float* wf_W = (const float*)d_in[4];
    const float* wf_b = (const float*)d_in[5];
    const float* b1_W = (const float*)d_in[6];
    const float* b1_b = (const float*)d_in[7];
    const float* v1_W = (const float*)d_in[8];
    const float* v1_b = (const float*)d_in[9];
    const float* v2_W = (const float*)d_in[10];
    const float* v2_b = (const float*)d_in[11];
    float* out = (float*)d_out;
    unsigned short* brep = (unsigned short*)d_ws;    // 180224 B of scratch

    repack_b<<<44, 256, 0, stream>>>(w1_W, wf_W, b1_W, v1_W, brep);
    qmix_main<<<256, 256, 0, stream>>>(agent_qs, states, brep,
                                       w1_b, wf_b, b1_b, v1_b, v2_W, v2_b, out);
}